// Round 15
// baseline (64.533 us; speedup 1.0000x reference)
//
#include <hip/hip_runtime.h>
#include <math.h>

#define B_TOTAL 2048
#define I_DIM   128
#define O_DIM   128
#define GK      68                  // G + k rows
#define NKNOT   71
#define W_ELEMS ((size_t)GK * I_DIM * O_DIM)    // 1114112
#define WS_MIN  (W_ELEMS * 2)                   // 2.23 MB bf16 copy
#define SLICE_B (GK * O_DIM * 2)                // 17408 B per i-slice

__device__ __forceinline__ float rdlanef(float v, int sl) {
    return __int_as_float(__builtin_amdgcn_readlane(__float_as_int(v), sl));
}
__device__ __forceinline__ unsigned short f2bf(float f) {   // RNE
    unsigned u = __float_as_uint(f);
    return (unsigned short)((u + 0x7fffu + ((u >> 16) & 1u)) >> 16);
}
__device__ __forceinline__ float bflo(unsigned u) { return __uint_as_float(u << 16); }
__device__ __forceinline__ float bfhi(unsigned u) { return __uint_as_float(u & 0xffff0000u); }

// de Boor coefs (exact ref order) for one (b,i)
__device__ __forceinline__ void coef_eval(float xv, const float* t_sh,
                                          float& c0, float& c1, float& c2,
                                          float& c3, float& c4, int& g0) {
    int ik = 3 + (int)floorf((xv + 1.0f) * 32.0f);
    ik = min(max(ik, 3), 66);
    while (ik < 66 && xv >= t_sh[ik + 1]) ++ik;
    while (ik > 3 && xv < t_sh[ik]) --ik;
    float l0, l1, l2, r0, r1, r2;
    float N0 = 1.0f, N1, N2, N3;
    l0 = xv - t_sh[ik];  r0 = t_sh[ik + 1] - xv;
    { float temp = N0 / (r0 + l0); N0 = r0 * temp; N1 = l0 * temp; }
    l1 = xv - t_sh[ik - 1];  r1 = t_sh[ik + 2] - xv;
    { float saved = 0.0f, temp;
      temp = N0 / (r0 + l1); N0 = saved + r0 * temp; saved = l1 * temp;
      temp = N1 / (r1 + l0); N1 = saved + r1 * temp; N2 = l0 * temp; }
    l2 = xv - t_sh[ik - 2];  r2 = t_sh[ik + 3] - xv;
    { float saved = 0.0f, temp;
      temp = N0 / (r0 + l2); N0 = saved + r0 * temp; saved = l2 * temp;
      temp = N1 / (r1 + l1); N1 = saved + r1 * temp; saved = l1 * temp;
      temp = N2 / (r2 + l0); N2 = saved + r2 * temp; N3 = l0 * temp; }
    c0 = N0; c1 = N1; c2 = N2; c3 = N3;
    c4 = xv / (1.0f + expf(-xv));
    g0 = ik - 3;
}

// w f32 [GK][I][O] -> bf16 [I][GK][O] (transpose g<->i, o innermost).
// 1088 blocks x 256 thr. All coalesced. (R9-proven.)
__global__ __launch_bounds__(256)
void wcvt(const float* __restrict__ w, unsigned short* __restrict__ wbf) {
    const int tid = threadIdx.x;
    const int p   = blockIdx.x * 8 + (tid >> 5);    // (g,i) in source order
    const int oq  = (tid & 31) * 4;
    const int g   = p >> 7;
    const int i   = p & 127;
    const float4 v = *(const float4*)(w + (size_t)p * O_DIM + oq);
    ushort4 o4;
    o4.x = f2bf(v.x); o4.y = f2bf(v.y); o4.z = f2bf(v.z); o4.w = f2bf(v.w);
    *(ushort4*)(wbf + ((size_t)i * GK + g) * O_DIM + oq) = o4;
}

// R9 skeleton (2048 blocks x 4 waves, full TLP) with halved VMEM:
// wave handles i in [32w, 32w+32); per (b,i) the two HALF-waves read
// rows {g0+h, g0+2+h} as dwordx2 (32 lanes x 8B = one full 256B row per
// half per instr) + 1 broadcast silu dwordx2 -> 3 VMEM vs R9's 5.
// Coefs via readlane + cndmask by half; silu added by h=0 only.
// Epilogue: shfl_xor(32) combine, lanes 0..31 write float4 psum, reduce.
__global__ __launch_bounds__(256, 8)
void flashkan_gather(const float* __restrict__ x,
                     const unsigned short* __restrict__ wbf,
                     const float* __restrict__ t,
                     float* __restrict__ out) {
    __shared__ float t_sh[NKNOT];
    __shared__ float psum[4][O_DIM];

    const int tid  = threadIdx.x;
    const int b    = blockIdx.x;
    const int wave = tid >> 6;
    const int lane = tid & 63;
    const int h    = lane >> 5;     // half: rows g0+h, g0+2+h
    const int l32  = lane & 31;     // o-quad: o = l32*4 .. +3

    if (tid < NKNOT) t_sh[tid] = t[tid];
    __syncthreads();

    // ---- coef phase: lane (l&31) owns i = wave*32 + (lane&31); halves dup ----
    float cf0, cf1, cf2, cf3, cf4;
    int   cg;
    coef_eval(x[(size_t)b * I_DIM + wave * 32 + l32], t_sh,
              cf0, cf1, cf2, cf3, cf4, cg);

    const char* wb = (const char*)wbf + (size_t)(wave * 32) * SLICE_B;
    const int lo8 = l32 * 8;        // byte offset within a 256B row

    float a0 = 0.0f, a1 = 0.0f, a2 = 0.0f, a3 = 0.0f;

    #pragma unroll
    for (int k = 0; k < 32; ++k) {
        const float c0 = rdlanef(cf0, k), c1 = rdlanef(cf1, k);
        const float c2 = rdlanef(cf2, k), c3 = rdlanef(cf3, k);
        const float c4 = rdlanef(cf4, k);
        const int   g0 = __builtin_amdgcn_readlane(cg, k);

        const float cA  = h ? c1 : c0;      // row g0+h
        const float cB  = h ? c3 : c2;      // row g0+2+h
        const float c4h = h ? 0.0f : c4;    // silu counted once

        const char* sl = wb + (size_t)k * SLICE_B;
        const uint2 uA = *(const uint2*)(sl + (g0 + h) * 256 + lo8);
        const uint2 uB = *(const uint2*)(sl + (g0 + 2 + h) * 256 + lo8);
        const uint2 su = *(const uint2*)(sl + 67 * 256 + lo8);  // bcast pair

        a0 += cA * bflo(uA.x) + cB * bflo(uB.x) + c4h * bflo(su.x);
        a1 += cA * bfhi(uA.x) + cB * bfhi(uB.x) + c4h * bfhi(su.x);
        a2 += cA * bflo(uA.y) + cB * bflo(uB.y) + c4h * bflo(su.y);
        a3 += cA * bfhi(uA.y) + cB * bfhi(uB.y) + c4h * bfhi(su.y);
    }

    // ---- combine halves: lanes l and l^32 share the same o-quad ----
    a0 += __shfl_xor(a0, 32);
    a1 += __shfl_xor(a1, 32);
    a2 += __shfl_xor(a2, 32);
    a3 += __shfl_xor(a3, 32);

    if (lane < 32) {
        *(float4*)&psum[wave][l32 * 4] = make_float4(a0, a1, a2, a3);
    }
    __syncthreads();

    if (tid < O_DIM) {
        out[(size_t)b * O_DIM + tid] =
            psum[0][tid] + psum[1][tid] + psum[2][tid] + psum[3][tid];
    }
}

// Fallback: R9 direct f32 gather (no ws needed).
__global__ __launch_bounds__(256)
void flashkan_gather_f32(const float* __restrict__ x,
                         const float* __restrict__ w,
                         const float* __restrict__ t,
                         float* __restrict__ out) {
    __shared__ float t_sh[NKNOT];
    __shared__ float psum[4][O_DIM];
    const int tid  = threadIdx.x;
    const int b    = blockIdx.x;
    const int wave = tid >> 6;
    const int lane = tid & 63;
    const int l32  = lane & 31;
    if (tid < NKNOT) t_sh[tid] = t[tid];
    __syncthreads();
    float cf0, cf1, cf2, cf3, cf4; int cg;
    coef_eval(x[(size_t)b * I_DIM + wave * 32 + l32], t_sh,
              cf0, cf1, cf2, cf3, cf4, cg);
    const int i_base = wave * 32;
    float ax = 0.0f, ay = 0.0f;
    #pragma unroll 8
    for (int k = 0; k < 32; ++k) {
        const float c0 = rdlanef(cf0, k), c1 = rdlanef(cf1, k);
        const float c2 = rdlanef(cf2, k), c3 = rdlanef(cf3, k);
        const float c4 = rdlanef(cf4, k);
        const int   g0 = __builtin_amdgcn_readlane(cg, k);
        const int i = i_base + k;
        const float2* base = (const float2*)(w + (size_t)i * O_DIM) + lane;
        const size_t rs = (size_t)I_DIM * O_DIM / 2;
        const float2 v0 = base[(size_t)g0 * rs];
        const float2 v1 = base[(size_t)(g0 + 1) * rs];
        const float2 v2 = base[(size_t)(g0 + 2) * rs];
        const float2 v3 = base[(size_t)(g0 + 3) * rs];
        const float2 v4 = base[(size_t)(GK - 1) * rs];
        ax += c0 * v0.x + c1 * v1.x + c2 * v2.x + c3 * v3.x + c4 * v4.x;
        ay += c0 * v0.y + c1 * v1.y + c2 * v2.y + c3 * v3.y + c4 * v4.y;
    }
    psum[wave][lane * 2]     = ax;
    psum[wave][lane * 2 + 1] = ay;
    __syncthreads();
    if (tid < O_DIM) {
        out[(size_t)b * O_DIM + tid] =
            psum[0][tid] + psum[1][tid] + psum[2][tid] + psum[3][tid];
    }
}

extern "C" void kernel_launch(void* const* d_in, const int* in_sizes, int n_in,
                              void* d_out, int out_size, void* d_ws, size_t ws_size,
                              hipStream_t stream) {
    const float* x = (const float*)d_in[0];
    const float* w = (const float*)d_in[1];
    const float* t = (const float*)d_in[2];
    float* out = (float*)d_out;

    if (ws_size >= WS_MIN) {
        unsigned short* wbf = (unsigned short*)d_ws;
        wcvt<<<(int)(W_ELEMS / (8 * 128)), 256, 0, stream>>>(w, wbf);  // 1088
        flashkan_gather<<<B_TOTAL, 256, 0, stream>>>(x, wbf, t, out);
    } else {
        flashkan_gather_f32<<<B_TOTAL, 256, 0, stream>>>(x, w, t, out);
    }
}

// Round 16
// 31.227 us; speedup vs baseline: 2.0666x; 2.0666x over previous
//
#include <hip/hip_runtime.h>
#include <math.h>

#define B_TOTAL 2048
#define I_DIM   128
#define O_DIM   128
#define GK      68                  // G + k rows in w
#define NKNOT   71
#define W_ELEMS ((size_t)GK * I_DIM * O_DIM)    // 1114112
#define WS_MIN  (W_ELEMS * 2)                   // 2.23 MB bf16 copy

__device__ __forceinline__ float rdlanef(float v, int l) {
    return __int_as_float(__builtin_amdgcn_readlane(__float_as_int(v), l));
}
__device__ __forceinline__ unsigned short f2bf(float f) {   // RNE
    unsigned u = __float_as_uint(f);
    return (unsigned short)((u + 0x7fffu + ((u >> 16) & 1u)) >> 16);
}
__device__ __forceinline__ float bflo(unsigned u) { return __uint_as_float(u << 16); }
__device__ __forceinline__ float bfhi(unsigned u) { return __uint_as_float(u & 0xffff0000u); }

// w f32 [GK][I][O] -> bf16 [I][GK][O] (transpose g<->i, o innermost).
// 1088 blocks x 256 thr; 8 (g,i) pairs/block x 32 o-quads. All coalesced.
__global__ __launch_bounds__(256)
void wcvt(const float* __restrict__ w, unsigned short* __restrict__ wbf) {
    const int tid = threadIdx.x;
    const int p   = blockIdx.x * 8 + (tid >> 5);    // (g,i) in source order
    const int oq  = (tid & 31) * 4;
    const int g   = p >> 7;
    const int i   = p & 127;
    const float4 v = *(const float4*)(w + (size_t)p * O_DIM + oq);
    ushort4 o4;
    o4.x = f2bf(v.x); o4.y = f2bf(v.y); o4.z = f2bf(v.z); o4.w = f2bf(v.w);
    *(ushort4*)(wbf + ((size_t)i * GK + g) * O_DIM + oq) = o4;
}

// One block per b: 256 thr = 4 waves, wave w handles i in [32w, 32w+32).
// Direct coalesced gathers from L2-resident bf16 w (2.23MB < 4MB per-XCD L2).
// Lane covers o = {2*lane, 2*lane+1} (one dword = 2 bf16). Rows g0..g0+3 of
// (i) are contiguous in [I][GK][O]: one SGPR base (readlane g0) + imm offsets.
// THE proven pattern (R9, 30.9us): wave-uniform row base + per-lane linear
// offset + full TLP (8 blocks/CU = 32 waves/CU). Every deviation measured
// slower (R10-R15). Cross-wave i-partials reduced via LDS psum.
__global__ __launch_bounds__(256, 8)
void flashkan_gather(const float* __restrict__ x,
                     const unsigned short* __restrict__ wbf,
                     const float* __restrict__ t,
                     float* __restrict__ out) {
    __shared__ float t_sh[NKNOT];
    __shared__ float psum[4][O_DIM];

    const int tid  = threadIdx.x;
    const int b    = blockIdx.x;
    const int wave = tid >> 6;
    const int lane = tid & 63;
    const int l32  = lane & 31;

    if (tid < NKNOT) t_sh[tid] = t[tid];
    __syncthreads();

    // ---- coef phase: every lane computes i = wave*32 + (lane&31) ----
    float cf0, cf1, cf2, cf3, cf4;
    int   cg;
    {
        const float xv = x[(size_t)b * I_DIM + wave * 32 + l32];

        int ik = 3 + (int)floorf((xv + 1.0f) * 32.0f);
        ik = min(max(ik, 3), 66);
        while (ik < 66 && xv >= t_sh[ik + 1]) ++ik;
        while (ik > 3 && xv < t_sh[ik]) --ik;

        float l0, l1, l2, r0, r1, r2;
        float N0 = 1.0f, N1, N2, N3;
        l0 = xv - t_sh[ik];
        r0 = t_sh[ik + 1] - xv;
        {
            float temp = N0 / (r0 + l0);
            N0 = r0 * temp;
            N1 = l0 * temp;
        }
        l1 = xv - t_sh[ik - 1];
        r1 = t_sh[ik + 2] - xv;
        {
            float saved = 0.0f, temp;
            temp = N0 / (r0 + l1);
            N0 = saved + r0 * temp;
            saved = l1 * temp;
            temp = N1 / (r1 + l0);
            N1 = saved + r1 * temp;
            N2 = l0 * temp;
        }
        l2 = xv - t_sh[ik - 2];
        r2 = t_sh[ik + 3] - xv;
        {
            float saved = 0.0f, temp;
            temp = N0 / (r0 + l2);
            N0 = saved + r0 * temp;
            saved = l2 * temp;
            temp = N1 / (r1 + l1);
            N1 = saved + r1 * temp;
            saved = l1 * temp;
            temp = N2 / (r2 + l0);
            N2 = saved + r2 * temp;
            N3 = l0 * temp;
        }
        cf0 = N0; cf1 = N1; cf2 = N2; cf3 = N3;
        cf4 = xv / (1.0f + expf(-xv));
        cg  = ik - 3;
    }

    // ---- gather-accumulate over this wave's 32 i ----
    const int i_base = wave * 32;
    float ax = 0.0f, ay = 0.0f;

    #pragma unroll
    for (int k = 0; k < 32; ++k) {
        const float c0 = rdlanef(cf0, k);
        const float c1 = rdlanef(cf1, k);
        const float c2 = rdlanef(cf2, k);
        const float c3 = rdlanef(cf3, k);
        const float c4 = rdlanef(cf4, k);
        const int   g0 = __builtin_amdgcn_readlane(cg, k);

        const int i = i_base + k;
        const unsigned* rp = (const unsigned*)(wbf + (((size_t)i * GK + g0) << 7)) + lane;
        const unsigned* sp = (const unsigned*)(wbf + (((size_t)i * GK + 67) << 7)) + lane;
        const unsigned u0 = rp[0];      // row g0
        const unsigned u1 = rp[64];     // row g0+1 (+256B)
        const unsigned u2 = rp[128];    // row g0+2
        const unsigned u3 = rp[192];    // row g0+3
        const unsigned u4 = *sp;        // silu row (g=67)

        ax += c0 * bflo(u0) + c1 * bflo(u1) + c2 * bflo(u2)
            + c3 * bflo(u3) + c4 * bflo(u4);
        ay += c0 * bfhi(u0) + c1 * bfhi(u1) + c2 * bfhi(u2)
            + c3 * bfhi(u3) + c4 * bfhi(u4);
    }

    psum[wave][lane * 2]     = ax;
    psum[wave][lane * 2 + 1] = ay;
    __syncthreads();

    if (tid < O_DIM) {
        out[(size_t)b * O_DIM + tid] =
            psum[0][tid] + psum[1][tid] + psum[2][tid] + psum[3][tid];
    }
}

// Fallback (ws too small for bf16 copy): direct f32 gather, same structure.
__global__ __launch_bounds__(256)
void flashkan_gather_f32(const float* __restrict__ x,
                         const float* __restrict__ w,
                         const float* __restrict__ t,
                         float* __restrict__ out) {
    __shared__ float t_sh[NKNOT];
    __shared__ float psum[4][O_DIM];
    const int tid  = threadIdx.x;
    const int b    = blockIdx.x;
    const int wave = tid >> 6;
    const int lane = tid & 63;
    const int l32  = lane & 31;
    if (tid < NKNOT) t_sh[tid] = t[tid];
    __syncthreads();
    float cf0, cf1, cf2, cf3, cf4; int cg;
    {
        const float xv = x[(size_t)b * I_DIM + wave * 32 + l32];
        int ik = 3 + (int)floorf((xv + 1.0f) * 32.0f);
        ik = min(max(ik, 3), 66);
        while (ik < 66 && xv >= t_sh[ik + 1]) ++ik;
        while (ik > 3 && xv < t_sh[ik]) --ik;
        float l0, l1, l2, r0, r1, r2;
        float N0 = 1.0f, N1, N2, N3;
        l0 = xv - t_sh[ik];  r0 = t_sh[ik + 1] - xv;
        { float temp = N0 / (r0 + l0); N0 = r0 * temp; N1 = l0 * temp; }
        l1 = xv - t_sh[ik - 1];  r1 = t_sh[ik + 2] - xv;
        { float saved = 0.0f, temp;
          temp = N0 / (r0 + l1); N0 = saved + r0 * temp; saved = l1 * temp;
          temp = N1 / (r1 + l0); N1 = saved + r1 * temp; N2 = l0 * temp; }
        l2 = xv - t_sh[ik - 2];  r2 = t_sh[ik + 3] - xv;
        { float saved = 0.0f, temp;
          temp = N0 / (r0 + l2); N0 = saved + r0 * temp; saved = l2 * temp;
          temp = N1 / (r1 + l1); N1 = saved + r1 * temp; saved = l1 * temp;
          temp = N2 / (r2 + l0); N2 = saved + r2 * temp; N3 = l0 * temp; }
        cf0 = N0; cf1 = N1; cf2 = N2; cf3 = N3;
        cf4 = xv / (1.0f + expf(-xv));
        cg  = ik - 3;
    }
    const int i_base = wave * 32;
    float ax = 0.0f, ay = 0.0f;
    #pragma unroll 8
    for (int k = 0; k < 32; ++k) {
        const float c0 = rdlanef(cf0, k), c1 = rdlanef(cf1, k);
        const float c2 = rdlanef(cf2, k), c3 = rdlanef(cf3, k);
        const float c4 = rdlanef(cf4, k);
        const int   g0 = __builtin_amdgcn_readlane(cg, k);
        const int i = i_base + k;
        const float2* base = (const float2*)(w + (size_t)i * O_DIM) + lane;
        const size_t rs = (size_t)I_DIM * O_DIM / 2;    // row stride in float2
        const float2 v0 = base[(size_t)g0 * rs];
        const float2 v1 = base[(size_t)(g0 + 1) * rs];
        const float2 v2 = base[(size_t)(g0 + 2) * rs];
        const float2 v3 = base[(size_t)(g0 + 3) * rs];
        const float2 v4 = base[(size_t)(GK - 1) * rs];
        ax += c0 * v0.x + c1 * v1.x + c2 * v2.x + c3 * v3.x + c4 * v4.x;
        ay += c0 * v0.y + c1 * v1.y + c2 * v2.y + c3 * v3.y + c4 * v4.y;
    }
    psum[wave][lane * 2]     = ax;
    psum[wave][lane * 2 + 1] = ay;
    __syncthreads();
    if (tid < O_DIM) {
        out[(size_t)b * O_DIM + tid] =
            psum[0][tid] + psum[1][tid] + psum[2][tid] + psum[3][tid];
    }
}

extern "C" void kernel_launch(void* const* d_in, const int* in_sizes, int n_in,
                              void* d_out, int out_size, void* d_ws, size_t ws_size,
                              hipStream_t stream) {
    const float* x = (const float*)d_in[0];
    const float* w = (const float*)d_in[1];
    const float* t = (const float*)d_in[2];
    float* out = (float*)d_out;

    if (ws_size >= WS_MIN) {
        unsigned short* wbf = (unsigned short*)d_ws;
        wcvt<<<(int)(W_ELEMS / (8 * 128)), 256, 0, stream>>>(w, wbf);  // 1088 blocks
        flashkan_gather<<<B_TOTAL, 256, 0, stream>>>(x, wbf, t, out);
    } else {
        flashkan_gather_f32<<<B_TOTAL, 256, 0, stream>>>(x, w, t, out);
    }
}